// Round 10
// baseline (569.093 us; speedup 1.0000x reference)
//
#include <hip/hip_runtime.h>
#include <hip/hip_fp8.h>
#include <cstdint>
#include <cmath>

// Problem constants
#define B_   4
#define C_   512
#define HW_  4096
#define G_   32
#define CPG_ 16
#define EPS_ 1e-6f
#define SCALE_ 0.04419417382415922f  // 1/sqrt(512)
#define PSCALE_ 0.0625f              // P pre-scale; cancels in acc/rowsum ratio
#define SEXPC_ 0.063758715306f       // SCALE * log2(e): exp(a*S)*2^-4 = 2^(a*SEXPC - 4)

// ---------------------------------------------------------------------------
// R18: fusion v3. sexp+pv (≈100us of 227.7) replaced by ONE flash-style
// kernel reusing R9(=R1)'s verified geometry (64-row Q panels, 256 blocks,
// FETCH 20.5 MB there) with a 1-barrier/iter software-pipelined schedule:
// S(t) || PV(t-1), P double-buffered in LDS, all 16 V loads issued before S
// (latency hides under 16 MFMA), K(t+1) cp16s covered by exp+PV+barrier.
// R1's 164us failure was 3 barriers/iter + exposed V loads, NOT fusion per
// se (it passed correctness; R8 proved blocks/CU don't matter). S/exp/P/PV/
// epilogue fragments lifted verbatim from the R1-passing kernel.
// ---------------------------------------------------------------------------

typedef __bf16 bf16_t;
typedef __bf16 bf16x8 __attribute__((ext_vector_type(8)));
typedef float  f32x4  __attribute__((ext_vector_type(4)));
typedef int    i32x4  __attribute__((ext_vector_type(4)));
typedef int    i32x8  __attribute__((ext_vector_type(8)));
typedef unsigned int u32;
typedef __hip_fp8_e4m3 fp8_t;  // OCP e4m3fn on gfx950

// Async global->LDS copy, 16B per lane. LDS dest is wave-uniform base + lane*16.
__device__ __forceinline__ void cp16(const void* g, void* l) {
  __builtin_amdgcn_global_load_lds((__attribute__((address_space(1))) u32*)(g),
                                   (__attribute__((address_space(3))) u32*)(l),
                                   16, 0, 0);
}

// Raw v_exp_f32 (2^x). s_nop 1 covers the trans->consumer wait-state.
__device__ __forceinline__ float fexp2(float x) {
  float r;
  asm("v_exp_f32 %0, %1\n\ts_nop 1" : "=v"(r) : "v"(x));
  return r;
}

__device__ __forceinline__ void zero_acc(f32x4 acc[4][4]) {
  f32x4 z = {0.f, 0.f, 0.f, 0.f};
#pragma unroll
  for (int i = 0; i < 4; ++i)
#pragma unroll
    for (int j = 0; j < 4; ++j) acc[i][j] = z;
}

// MX-fp8 BT GEMM mainloop (BK=128), 128^2 tile — verified R12 structure.
template <bool ROWSUM, int SA = 0x7F, int SB = 0x7F>
__device__ __forceinline__ void gemm_bt_mx(const unsigned char* __restrict__ A,
                                           const unsigned char* __restrict__ B,
                                           int K, int lda, int ldb,
                                           f32x4 acc[4][4], f32x4 accl[4],
                                           unsigned char* AsB, unsigned char* BsB) {
  const int tid  = threadIdx.x;
  const int wave = tid >> 6;
  const int lane = tid & 63;
  const int wm = (wave >> 1) * 64;
  const int wn = (wave & 1) * 64;
  const int srow = lane >> 3;
  const int gch  = ((lane & 7) - srow) & 7;
  const unsigned char* gA = A + (size_t)(wave * 32 + srow) * lda + gch * 16;
  const unsigned char* gB = B + (size_t)(wave * 32 + srow) * ldb + gch * 16;
  const int lofs = wave * 32 * 128;
  const int fr = lane & 15;
  const int q  = lane >> 4;
  const int co0 = ((2 * q     + fr) & 7) * 16;
  const int co1 = ((2 * q + 1 + fr) & 7) * 16;
  const i32x8 vones = {0x38383838, 0x38383838, 0x38383838, 0x38383838,
                       0x38383838, 0x38383838, 0x38383838, 0x38383838};

  const int nT = K >> 7;
#pragma unroll
  for (int cc = 0; cc < 4; ++cc) {
    cp16(gA + (size_t)(cc * 8) * lda, AsB + lofs + cc * 1024);
    cp16(gB + (size_t)(cc * 8) * ldb, BsB + lofs + cc * 1024);
  }
  gA += 128; gB += 128;

#pragma unroll 1
  for (int t = 0; t < nT; ++t) {
    const int cur = t & 1;
    if (t + 1 < nT) {
#pragma unroll
      for (int cc = 0; cc < 4; ++cc) {
        cp16(gA + (size_t)(cc * 8) * lda, AsB + (cur ^ 1) * 16384 + lofs + cc * 1024);
        cp16(gB + (size_t)(cc * 8) * ldb, BsB + (cur ^ 1) * 16384 + lofs + cc * 1024);
      }
      gA += 128; gB += 128;
      asm volatile("s_waitcnt vmcnt(8)" ::: "memory");
    } else {
      asm volatile("s_waitcnt vmcnt(0)" ::: "memory");
    }
    __builtin_amdgcn_s_barrier();

    i32x8 a[4], b[4];
    const unsigned char* Ab = AsB + cur * 16384;
    const unsigned char* Bb = BsB + cur * 16384;
#pragma unroll
    for (int i = 0; i < 4; ++i) {
      const int ro = (wm + i * 16 + fr) * 128;
      i32x4 lo = *(const i32x4*)(Ab + ro + co0);
      i32x4 hi = *(const i32x4*)(Ab + ro + co1);
      a[i] = __builtin_shufflevector(lo, hi, 0, 1, 2, 3, 4, 5, 6, 7);
    }
#pragma unroll
    for (int j = 0; j < 4; ++j) {
      const int ro = (wn + j * 16 + fr) * 128;
      i32x4 lo = *(const i32x4*)(Bb + ro + co0);
      i32x4 hi = *(const i32x4*)(Bb + ro + co1);
      b[j] = __builtin_shufflevector(lo, hi, 0, 1, 2, 3, 4, 5, 6, 7);
    }
    __builtin_amdgcn_s_setprio(1);
#pragma unroll
    for (int i = 0; i < 4; ++i) {
#pragma unroll
      for (int j = 0; j < 4; ++j)
        acc[i][j] = __builtin_amdgcn_mfma_scale_f32_16x16x128_f8f6f4(
            a[i], b[j], acc[i][j], 0, 0, 0, SA, 0, SB);
      if (ROWSUM)
        accl[i] = __builtin_amdgcn_mfma_scale_f32_16x16x128_f8f6f4(
            a[i], vones, accl[i], 0, 0, 0, SA, 0, 0x7F);
    }
    __builtin_amdgcn_s_setprio(0);
    __builtin_amdgcn_s_barrier();
  }
}

// ---------------- prep: GroupNorm partials + weight casts (merged) ----------

__global__ void __launch_bounds__(256) prep_kernel(const float* __restrict__ x,
                                                   float* __restrict__ stats,
                                                   const float* __restrict__ qkv_w,
                                                   const float* __restrict__ proj_w,
                                                   fp8_t* __restrict__ wqkv8,
                                                   fp8_t* __restrict__ wproj8) {
  __shared__ float rs[256], rss[256];
  const int n = blockIdx.x;
  if (n < 1024) {
    const int bg = n >> 3;       // group id 0..127
    const int ch = n & 7;        // hw chunk 0..7
    const float4* base = (const float4*)(x + (size_t)bg * (CPG_ * HW_)) +
                         (size_t)ch * (CPG_ * HW_ / 4 / 8);
    float s = 0.f, ss = 0.f;
    for (int i = threadIdx.x; i < CPG_ * HW_ / 4 / 8; i += 256) {
      float4 v = base[i];
      s  += v.x + v.y + v.z + v.w;
      ss += v.x * v.x + v.y * v.y + v.z * v.z + v.w * v.w;
    }
    rs[threadIdx.x] = s; rss[threadIdx.x] = ss;
    __syncthreads();
    for (int st = 128; st > 0; st >>= 1) {
      if ((int)threadIdx.x < st) {
        rs[threadIdx.x]  += rs[threadIdx.x + st];
        rss[threadIdx.x] += rss[threadIdx.x + st];
      }
      __syncthreads();
    }
    if (threadIdx.x == 0) {
      stats[(bg * 8 + ch) * 2 + 0] = rs[0];
      stats[(bg * 8 + ch) * 2 + 1] = rss[0];
    }
  } else {
    const int idx = (n - 1024) * 256 + threadIdx.x;   // quad index
    const int t = idx * 4;
    const int nq = 1536 * 512;
    if (t < nq) {
      u32 dw = 0;
      dw = (u32)__builtin_amdgcn_cvt_pk_fp8_f32(qkv_w[t] * 16.f, qkv_w[t + 1] * 16.f, (int)dw, false);
      dw = (u32)__builtin_amdgcn_cvt_pk_fp8_f32(qkv_w[t + 2] * 16.f, qkv_w[t + 3] * 16.f, (int)dw, true);
      *(u32*)((unsigned char*)wqkv8 + t) = dw;
    } else {
      const int tt = t - nq;          // o*512 + p, p multiple of 4
      const int o = tt >> 9;
      const int p = tt & 511;
      float v[4];
#pragma unroll
      for (int e = 0; e < 4; ++e) {
        const int pe = p + e;
        const int off = pe & 63;
        const int c = (pe & ~63) + ((off & 3) << 4) + (off >> 2);  // sigma(pe)
        v[e] = proj_w[(o << 9) + c] * 16.f;
      }
      u32 dw = 0;
      dw = (u32)__builtin_amdgcn_cvt_pk_fp8_f32(v[0], v[1], (int)dw, false);
      dw = (u32)__builtin_amdgcn_cvt_pk_fp8_f32(v[2], v[3], (int)dw, true);
      *(u32*)((unsigned char*)wproj8 + tt) = dw;
    }
  }
}

// normalize + transpose: x[b][c][i] (fp32) -> xnT8[b][i][c] (fp8, plain order)
__global__ void __launch_bounds__(256) norm_tr_kernel(const float* __restrict__ x,
                                                      const float* __restrict__ stats,
                                                      const float* __restrict__ nw,
                                                      const float* __restrict__ nb,
                                                      fp8_t* __restrict__ xnT8) {
  __shared__ float tile[64][65];   // [c_off][i_off]
  const int b  = blockIdx.z;
  const int i0 = blockIdx.x * 64;   // hw
  const int c0 = blockIdx.y * 64;   // channel
  const int tx = threadIdx.x & 63;
  const int ty = threadIdx.x >> 6;  // 0..3
  const int cbase = c0 + ty * 16;
  const int g = cbase >> 4;         // group const across r (16 channels per ty)
  const float inv = 1.f / (float)(CPG_ * HW_);
  float sum = 0.f, ssum = 0.f;
#pragma unroll
  for (int ch = 0; ch < 8; ++ch) {
    sum  += stats[((b * G_ + g) * 8 + ch) * 2 + 0];
    ssum += stats[((b * G_ + g) * 8 + ch) * 2 + 1];
  }
  const float mean = sum * inv;
  const float rstd = rsqrtf(ssum * inv - mean * mean + EPS_);
#pragma unroll
  for (int r = 0; r < 16; ++r) {
    const int c = cbase + r;
    float v = x[((size_t)b * C_ + c) * HW_ + i0 + tx];
    tile[ty * 16 + r][tx] = (v - mean) * rstd * nw[c] + nb[c];
  }
  __syncthreads();
  const int il = threadIdx.x >> 2;
  const int q4 = threadIdx.x & 3;
#pragma unroll
  for (int m = 0; m < 4; ++m) {
    const int cq = q4 + m * 4;     // 0..15
    u32 dw = 0;
    dw = (u32)__builtin_amdgcn_cvt_pk_fp8_f32(tile[cq * 4 + 0][il], tile[cq * 4 + 1][il], (int)dw, false);
    dw = (u32)__builtin_amdgcn_cvt_pk_fp8_f32(tile[cq * 4 + 2][il], tile[cq * 4 + 3][il], (int)dw, true);
    *(u32*)((unsigned char*)xnT8 + ((size_t)b * HW_ + i0 + il) * C_ + c0 + cq * 4) = dw;
  }
}

// ---------------- GEMM kernels ----------------

// Merged qk+v projections.
__global__ void __launch_bounds__(256) qkv_gemm_kernel(const fp8_t* __restrict__ xnT8,
                                                       const fp8_t* __restrict__ wqkv8,
                                                       const float* __restrict__ qkv_b,
                                                       fp8_t* __restrict__ QKt8,
                                                       fp8_t* __restrict__ V8) {
  __shared__ __align__(16) unsigned char As[2 * 16384];
  __shared__ __align__(16) unsigned char Bs[2 * 16384];
  const int n = blockIdx.x;
  const int lane = threadIdx.x & 63, wave = threadIdx.x >> 6;
  const int wm = (wave >> 1) * 64, wn = (wave & 1) * 64;
  const int fr = lane & 15, q = lane >> 4;
  f32x4 acc[4][4]; zero_acc(acc);

  if (n < 1024) {
    const int xb = n & 7, yb = (n >> 3) & 31, b = n >> 8;
    const unsigned char* A  = (const unsigned char*)xnT8 + ((size_t)b * HW_ + yb * 128) * C_;
    const unsigned char* Bp = (const unsigned char*)wqkv8 + (size_t)xb * 128 * C_;
    gemm_bt_mx<false, 0x7F, 0x7B>(A, Bp, C_, C_, C_, acc, nullptr, As, Bs);
    const int r0 = yb * 128 + wm + (q << 2);
    const int cb = xb * 128 + wn;
    float bias[4];
#pragma unroll
    for (int j = 0; j < 4; ++j) bias[j] = qkv_b[cb + fr + j * 16];
#pragma unroll
    for (int i = 0; i < 4; ++i)
#pragma unroll
      for (int r = 0; r < 4; ++r) {
        const int row = r0 + i * 16 + r;
        u32 dw = 0;
        dw = (u32)__builtin_amdgcn_cvt_pk_fp8_f32(acc[i][0][r] + bias[0],
                                                  acc[i][1][r] + bias[1], (int)dw, false);
        dw = (u32)__builtin_amdgcn_cvt_pk_fp8_f32(acc[i][2][r] + bias[2],
                                                  acc[i][3][r] + bias[3], (int)dw, true);
        *(u32*)((unsigned char*)QKt8 + ((size_t)b * HW_ + row) * 1024 + cb + fr * 4) = dw;
      }
  } else {
    const int m = n - 1024;
    const int xb = m & 31, yb = (m >> 5) & 3, b = m >> 7;
    const unsigned char* A  = (const unsigned char*)wqkv8 + (size_t)(1024 + yb * 128) * C_;
    const unsigned char* Bp = (const unsigned char*)xnT8 + ((size_t)b * HW_ + xb * 128) * C_;
    gemm_bt_mx<false, 0x7B, 0x7F>(A, Bp, C_, C_, C_, acc, nullptr, As, Bs);
    const int r0 = yb * 128 + wm + (q << 2);
    const int cb = xb * 128 + wn;
#pragma unroll
    for (int i = 0; i < 4; ++i)
#pragma unroll
      for (int r = 0; r < 4; ++r) {
        const int row = r0 + i * 16 + r;        // c channel (row of V8)
        const float bias = qkv_b[1024 + row];
        u32 dw = 0;
        dw = (u32)__builtin_amdgcn_cvt_pk_fp8_f32(acc[i][0][r] + bias,
                                                  acc[i][1][r] + bias, (int)dw, false);
        dw = (u32)__builtin_amdgcn_cvt_pk_fp8_f32(acc[i][2][r] + bias,
                                                  acc[i][3][r] + bias, (int)dw, true);
        *(u32*)((unsigned char*)V8 + ((size_t)b * C_ + row) * HW_ + cb + fr * 4) = dw;
      }
  }
}

// ---------------------------------------------------------------------------
// Fused attention v3: hmT8 = fp8(16 * (exp(s*QK^T) . V) / rowsum), P never
// touches global. 256 blocks (4 batches x 64-row Q panels), 8 waves.
//   wave: ih = w&1 (32-row half), jq = w>>1 (S col quarter / PV ch group cg).
// Schedule per iter t (1 barrier): see file header. LDS: K dbuf 2x64KB +
// P dbuf 2x8KB = 144 KB.
// ---------------------------------------------------------------------------
__global__ void __launch_bounds__(512, 2)
fused_attn_kernel(const fp8_t* __restrict__ QKt8, const fp8_t* __restrict__ V8,
                  fp8_t* __restrict__ hmT8) {
  __shared__ __align__(16) unsigned char kbuf[2][65536];
  __shared__ __align__(16) unsigned char pbuf[2][8192];

  // XCD decode (R1-verified L2 behavior): batch b -> XCDs {2b, 2b+1}
  const int n     = blockIdx.x;
  const int xcd   = n & 7;
  const int b     = xcd >> 1;
  const int panel = (xcd & 1) * 32 + (n >> 3);   // 0..63

  const int tid  = threadIdx.x;
  const int lane = tid & 63;
  const int wave = tid >> 6;
  const int fr   = lane & 15;
  const int q    = lane >> 4;
  const int ih   = wave & 1;
  const int jq   = wave >> 1;
  const int cg   = wave >> 1;

  const unsigned char* QKb = (const unsigned char*)QKt8 + (size_t)b * HW_ * 1024;
  const unsigned char* gK  = QKb + 512;   // K half of qkv columns

  const int sch = tid & 31;   // staging chunk within a 512-B row
  const int srw = tid >> 5;   // staging row within a 16-row pass

  // ---- prologue: stage Q (64x512) into kbuf[0], preload qf ----
#pragma unroll
  for (int p = 0; p < 4; ++p) {
    const int row = p * 16 + srw;
    cp16(QKb + (size_t)(panel * 64 + row) * 1024 + (((sch - row) & 31) << 4),
         kbuf[0] + row * 512 + sch * 16);
  }
  asm volatile("s_waitcnt vmcnt(0)" ::: "memory");
  __builtin_amdgcn_s_barrier();

  i32x8 qf[2][4];
#pragma unroll
  for (int ii = 0; ii < 2; ++ii) {
    const int row = ih * 32 + ii * 16 + fr;
    const unsigned char* qr = kbuf[0] + row * 512;
#pragma unroll
    for (int k = 0; k < 4; ++k) {
      i32x4 lo = *(const i32x4*)(qr + (((k * 8 + 2 * q + row) & 31) << 4));
      i32x4 hi = *(const i32x4*)(qr + (((k * 8 + 2 * q + 1 + row) & 31) << 4));
      qf[ii][k] = __builtin_shufflevector(lo, hi, 0, 1, 2, 3, 4, 5, 6, 7);
    }
  }
  asm volatile("s_waitcnt lgkmcnt(0)" ::: "memory");
  __builtin_amdgcn_s_barrier();   // all waves done reading Q region

  // ---- stage K(0) into kbuf[0] ----
#pragma unroll
  for (int p = 0; p < 8; ++p) {
    const int row = p * 16 + srw;
    cp16(gK + (size_t)row * 1024 + (((sch - row) & 31) << 4),
         kbuf[0] + row * 512 + sch * 16);
  }

  f32x4 pvacc[2][8];
  f32x4 accl[2];
  {
    f32x4 z = {0.f, 0.f, 0.f, 0.f};
#pragma unroll
    for (int i = 0; i < 2; ++i) {
#pragma unroll
      for (int j = 0; j < 8; ++j) pvacc[i][j] = z;
      accl[i] = z;
    }
  }
  const i32x8 vones = {0x38383838, 0x38383838, 0x38383838, 0x38383838,
                       0x38383838, 0x38383838, 0x38383838, 0x38383838};

  const unsigned char* vbase = (const unsigned char*)V8 +
      ((size_t)b * C_ + cg * 128 + fr) * HW_ + q * 32;

  const int kr0 = jq * 32 + fr;
  const int kr1 = kr0 + 16;
  const int offb = (jq >> 1) * 64 + fr * 4 + (jq & 1) * 2;  // P stored byte pos

  // S-phase macro pieces (R1-verified formulas)
#define S_PHASE(KB, SA0, SA1)                                                  \
  {                                                                            \
    const unsigned char* k0p = (KB) + kr0 * 512;                               \
    const unsigned char* k1p = (KB) + kr1 * 512;                               \
    _Pragma("unroll")                                                          \
    for (int k = 0; k < 4; ++k) {                                              \
      i32x4 l0 = *(const i32x4*)(k0p + (((k * 8 + 2 * q + kr0) & 31) << 4));   \
      i32x4 h0 = *(const i32x4*)(k0p + (((k * 8 + 2 * q + 1 + kr0) & 31) << 4));\
      i32x4 l1 = *(const i32x4*)(k1p + (((k * 8 + 2 * q + kr1) & 31) << 4));   \
      i32x4 h1 = *(const i32x4*)(k1p + (((k * 8 + 2 * q + 1 + kr1) & 31) << 4));\
      i32x8 kf0 = __builtin_shufflevector(l0, h0, 0, 1, 2, 3, 4, 5, 6, 7);     \
      i32x8 kf1 = __builtin_shufflevector(l1, h1, 0, 1, 2, 3, 4, 5, 6, 7);     \
      _Pragma("unroll")                                                        \
      for (int ii = 0; ii < 2; ++ii) {                                         \
        SA0[ii] = __builtin_amdgcn_mfma_scale_f32_16x16x128_f8f6f4(            \
            qf[ii][k], kf0, SA0[ii], 0, 0, 0, 0x7F, 0, 0x7F);                  \
        SA1[ii] = __builtin_amdgcn_mfma_scale_f32_16x16x128_f8f6f4(            \
            qf[ii][k], kf1, SA1[ii], 0, 0, 0, 0x7F, 0, 0x7F);                  \
      }                                                                        \
    }                                                                          \
  }

#define EXP_TO_P(PB, SA0, SA1)                                                 \
  {                                                                            \
    _Pragma("unroll")                                                          \
    for (int ii = 0; ii < 2; ++ii)                                             \
      _Pragma("unroll")                                                        \
      for (int r = 0; r < 4; ++r) {                                            \
        const int row = ih * 32 + ii * 16 + q * 4 + r;                         \
        float e0 = fexp2(fmaf(SA0[ii][r], SEXPC_, -4.0f));                     \
        float e1 = fexp2(fmaf(SA1[ii][r], SEXPC_, -4.0f));                     \
        u32 dw = (u32)__builtin_amdgcn_cvt_pk_fp8_f32(e0, e1, 0, false);       \
        *(unsigned short*)((PB) + row * 128 + ((((offb >> 4) + row) & 7) << 4) \
                           + (offb & 15)) = (unsigned short)dw;                \
      }                                                                        \
  }

  // ---- peel t = 0: S(0) + exp(0) -> pbuf[0]; stage K(1) ----
  {
    asm volatile("s_waitcnt vmcnt(0)" ::: "memory");  // K(0) resident
    __builtin_amdgcn_s_barrier();
    f32x4 s0[2], s1[2];
    {
      f32x4 z = {0.f, 0.f, 0.f, 0.f};
      s0[0] = z; s0[1] = z; s1[0] = z; s1[1] = z;
    }
    S_PHASE(kbuf[0], s0, s1)
#pragma unroll
    for (int p = 0; p < 8; ++p) {
      const int row = p * 16 + srw;
      cp16(gK + (size_t)(128 + row) * 1024 + (((sch - row) & 31) << 4),
           kbuf[1] + row * 512 + sch * 16);
    }
    EXP_TO_P(pbuf[0], s0, s1)
    asm volatile("s_waitcnt lgkmcnt(0) vmcnt(0)" ::: "memory");
    __builtin_amdgcn_s_barrier();   // P(0) visible, K(1) resident
  }

  // ---- main loop t = 1..31: S(t) || PV(t-1) ----
#pragma unroll 1
  for (int t = 1; t < 32; ++t) {
    const unsigned char* kb = kbuf[t & 1];          // K(t)
    const unsigned char* pb = pbuf[(t & 1) ^ 1];    // P(t-1)
    unsigned char* pw = pbuf[t & 1];                // P(t) dest

    // pa(t-1) reads + all 16 V(t-1) loads (latency hides under S)
    i32x8 pa[2];
#pragma unroll
    for (int ii = 0; ii < 2; ++ii) {
      const int prow = ih * 32 + ii * 16 + fr;
      const unsigned char* pp = pb + prow * 128;
      i32x4 lo = *(const i32x4*)(pp + (((2 * q + prow) & 7) << 4));
      i32x4 hi = *(const i32x4*)(pp + (((2 * q + 1 + prow) & 7) << 4));
      pa[ii] = __builtin_shufflevector(lo, hi, 0, 1, 2, 3, 4, 5, 6, 7);
    }
    const unsigned char* vp = vbase + (size_t)(t - 1) * 128;
    i32x4 vl[8], vh[8];
#pragma unroll
    for (int c = 0; c < 8; ++c) {
      vl[c] = *(const i32x4*)(vp + (size_t)(c * 16) * HW_);
      vh[c] = *(const i32x4*)(vp + (size_t)(c * 16) * HW_ + 16);
    }

    // S(t)
    f32x4 s0[2], s1[2];
    {
      f32x4 z = {0.f, 0.f, 0.f, 0.f};
      s0[0] = z; s0[1] = z; s1[0] = z; s1[1] = z;
    }
    __builtin_amdgcn_s_setprio(1);
    S_PHASE(kb, s0, s1)
    __builtin_amdgcn_s_setprio(0);

    // stage K(t+1) (after V loads -> vmcnt FIFO: 16 V then 8 cp16)
    if (t < 31) {
#pragma unroll
      for (int p = 0; p < 8; ++p) {
        const int row = p * 16 + srw;
        cp16(gK + (size_t)((t + 1) * 128 + row) * 1024 + (((sch - row) & 31) << 4),
             kbuf[(t + 1) & 1] + row * 512 + sch * 16);
      }
    }

    // exp(t) -> P(t)
    EXP_TO_P(pw, s0, s1)

    // V(t-1) resident (oldest 16 drained; K(t+1) cp16s keep flying)
    if (t < 31) {
      asm volatile("s_waitcnt vmcnt(8)" ::: "memory");
    } else {
      asm volatile("s_waitcnt vmcnt(0)" ::: "memory");
    }

    // PV(t-1)
    __builtin_amdgcn_s_setprio(1);
#pragma unroll
    for (int c = 0; c < 8; ++c) {
      i32x8 v = __builtin_shufflevector(vl[c], vh[c], 0, 1, 2, 3, 4, 5, 6, 7);
      pvacc[0][c] = __builtin_amdgcn_mfma_scale_f32_16x16x128_f8f6f4(
          pa[0], v, pvacc[0][c], 0, 0, 0, 0x7F, 0, 0x7F);
      pvacc[1][c] = __builtin_amdgcn_mfma_scale_f32_16x16x128_f8f6f4(
          pa[1], v, pvacc[1][c], 0, 0, 0, 0x7F, 0, 0x7F);
    }
    accl[0] = __builtin_amdgcn_mfma_scale_f32_16x16x128_f8f6f4(
        pa[0], vones, accl[0], 0, 0, 0, 0x7F, 0, 0x7F);
    accl[1] = __builtin_amdgcn_mfma_scale_f32_16x16x128_f8f6f4(
        pa[1], vones, accl[1], 0, 0, 0, 0x7F, 0, 0x7F);
    __builtin_amdgcn_s_setprio(0);

    // P(t) writes + all ds reads drained; K(t+1) resident -> single barrier
    asm volatile("s_waitcnt lgkmcnt(0) vmcnt(0)" ::: "memory");
    __builtin_amdgcn_s_barrier();
  }

  // ---- epilogue PV(31) ----
  {
    const unsigned char* pb = pbuf[1];   // P(31), t=31 wrote pbuf[31&1]=1
    i32x8 pa[2];
#pragma unroll
    for (int ii = 0; ii < 2; ++ii) {
      const int prow = ih * 32 + ii * 16 + fr;
      const unsigned char* pp = pb + prow * 128;
      i32x4 lo = *(const i32x4*)(pp + (((2 * q + prow) & 7) << 4));
      i32x4 hi = *(const i32x4*)(pp + (((2 * q + 1 + prow) & 7) << 4));
      pa[ii] = __builtin_shufflevector(lo, hi, 0, 1, 2, 3, 4, 5, 6, 7);
    }
    const unsigned char* vp = vbase + (size_t)31 * 128;
#pragma unroll
    for (int c = 0; c < 8; ++c) {
      i32x4 vl = *(const i32x4*)(vp + (size_t)(c * 16) * HW_);
      i32x4 vh = *(const i32x4*)(vp + (size_t)(c * 16) * HW_ + 16);
      i32x8 v = __builtin_shufflevector(vl, vh, 0, 1, 2, 3, 4, 5, 6, 7);
      pvacc[0][c] = __builtin_amdgcn_mfma_scale_f32_16x16x128_f8f6f4(
          pa[0], v, pvacc[0][c], 0, 0, 0, 0x7F, 0, 0x7F);
      pvacc[1][c] = __builtin_amdgcn_mfma_scale_f32_16x16x128_f8f6f4(
          pa[1], v, pvacc[1][c], 0, 0, 0, 0x7F, 0, 0x7F);
    }
    accl[0] = __builtin_amdgcn_mfma_scale_f32_16x16x128_f8f6f4(
        pa[0], vones, accl[0], 0, 0, 0, 0x7F, 0, 0x7F);
    accl[1] = __builtin_amdgcn_mfma_scale_f32_16x16x128_f8f6f4(
        pa[1], vones, accl[1], 0, 0, 0, 0x7F, 0, 0x7F);
  }

  // ---- hmT8 epilogue (R1-verified store pattern) ----
  unsigned char* hb = (unsigned char*)hmT8 + (size_t)b * HW_ * C_;
#pragma unroll
  for (int ii = 0; ii < 2; ++ii)
#pragma unroll
    for (int r = 0; r < 4; ++r) {
      const int row = panel * 64 + ih * 32 + ii * 16 + q * 4 + r;
      const float rl = 16.f * __builtin_amdgcn_rcpf(accl[ii][r]);
#pragma unroll
      for (int g = 0; g < 2; ++g) {
        u32 dw = 0;
        dw = (u32)__builtin_amdgcn_cvt_pk_fp8_f32(pvacc[ii][g * 4 + 0][r] * rl,
                                                  pvacc[ii][g * 4 + 1][r] * rl, (int)dw, false);
        dw = (u32)__builtin_amdgcn_cvt_pk_fp8_f32(pvacc[ii][g * 4 + 2][r] * rl,
                                                  pvacc[ii][g * 4 + 3][r] * rl, (int)dw, true);
        *(u32*)(hb + (size_t)row * C_ + cg * 128 + g * 64 + fr * 4) = dw;
      }
    }
}

// out[b][o][i] = x[b][o][i] + proj_b[o] + (wproj8*2^-4)(sigma) . (hmT8*2^-4)(sigma)
__global__ void __launch_bounds__(256) proj_gemm_kernel(const fp8_t* __restrict__ wproj8,
                                                        const fp8_t* __restrict__ hmT8,
                                                        const float* __restrict__ proj_b,
                                                        const float* __restrict__ x,
                                                        float* __restrict__ out) {
  __shared__ __align__(16) unsigned char As[2 * 16384];
  __shared__ __align__(16) unsigned char Bs[2 * 16384];
  const int b = blockIdx.z;
  f32x4 acc[4][4]; zero_acc(acc);
  const unsigned char* A  = (const unsigned char*)wproj8 + (size_t)blockIdx.y * 128 * C_;
  const unsigned char* Bp = (const unsigned char*)hmT8 + ((size_t)b * HW_ + blockIdx.x * 128) * C_;
  gemm_bt_mx<false, 0x7B, 0x7B>(A, Bp, C_, C_, C_, acc, nullptr, As, Bs);
  const int lane = threadIdx.x & 63, wave = threadIdx.x >> 6;
  const int wm = (wave >> 1) * 64, wn = (wave & 1) * 64;
  const int r0 = blockIdx.y * 128 + wm + ((lane >> 4) << 2);
  const int c0 = blockIdx.x * 128 + wn + (lane & 15);
#pragma unroll
  for (int i = 0; i < 4; ++i)
#pragma unroll
    for (int r = 0; r < 4; ++r) {
      const int row = r0 + i * 16 + r;
      const float bias = proj_b[row];
#pragma unroll
      for (int j = 0; j < 4; ++j) {
        const int col = c0 + j * 16;
        const size_t idx = ((size_t)b * C_ + row) * HW_ + col;
        out[idx] = x[idx] + bias + acc[i][j][r];
      }
    }
}

// ---------------- launch ----------------
// Workspace layout (bytes), total ~43 MB (P8 not materialized):
//   wqkv8  fp8 [1536][512] (x16)         786,432
//   wproj8 fp8 [512][512] (x16, sigma)   262,144
//   stats  f32 [128][8][2]                 8,192
//   xnT8   fp8 [4][4096][512]          8,388,608
//   QKt8   fp8 [4][4096][1024](sig)   16,777,216
//   V8     fp8 [4][512][4096] (sig)    8,388,608
//   hmT8   fp8 [4][4096][512] (x16,sig) 8,388,608
extern "C" void kernel_launch(void* const* d_in, const int* in_sizes, int n_in,
                              void* d_out, int out_size, void* d_ws, size_t ws_size,
                              hipStream_t stream) {
  const float* x      = (const float*)d_in[0];
  const float* norm_w = (const float*)d_in[1];
  const float* norm_b = (const float*)d_in[2];
  const float* qkv_w  = (const float*)d_in[3];
  const float* qkv_b  = (const float*)d_in[4];
  const float* proj_w = (const float*)d_in[5];
  const float* proj_b = (const float*)d_in[6];
  float* out = (float*)d_out;

  char* ws = (char*)d_ws;
  size_t o = 0;
  fp8_t* wqkv8  = (fp8_t*)(ws + o); o += (size_t)1536 * 512;
  fp8_t* wproj8 = (fp8_t*)(ws + o); o += (size_t)512 * 512;
  float* stats  = (float*)(ws + o); o += 128 * 8 * 2 * 4;
  fp8_t* xnT8   = (fp8_t*)(ws + o); o += (size_t)B_ * HW_ * C_;
  fp8_t* QKt8   = (fp8_t*)(ws + o); o += (size_t)B_ * HW_ * 1024;
  fp8_t* V8     = (fp8_t*)(ws + o); o += (size_t)B_ * C_ * HW_;
  fp8_t* hmT8   = (fp8_t*)(ws + o); o += (size_t)B_ * HW_ * C_;

  prep_kernel<<<2048, 256, 0, stream>>>(x, stats, qkv_w, proj_w, wqkv8, wproj8);
  norm_tr_kernel<<<dim3(HW_ / 64, C_ / 64, B_), 256, 0, stream>>>(x, stats, norm_w, norm_b, xnT8);
  qkv_gemm_kernel<<<1536, 256, 0, stream>>>(xnT8, wqkv8, qkv_b, QKt8, V8);
  fused_attn_kernel<<<256, 512, 0, stream>>>(QKt8, V8, hmT8);
  proj_gemm_kernel<<<dim3(HW_ / 128, C_ / 128, B_), 256, 0, stream>>>(
      wproj8, hmT8, proj_b, x, out);
}

// Round 11
// 331.463 us; speedup vs baseline: 1.7169x; 1.7169x over previous
//
#include <hip/hip_runtime.h>
#include <hip/hip_fp8.h>
#include <cstdint>
#include <cmath>

// Problem constants
#define B_   4
#define C_   512
#define HW_  4096
#define G_   32
#define CPG_ 16
#define EPS_ 1e-6f
#define SCALE_ 0.04419417382415922f  // 1/sqrt(512)
#define PSCALE_ 0.0625f              // P pre-scale; cancels in acc/rowsum ratio
#define SEXPC_ 0.063758715306f       // SCALE * log2(e): exp(a*S)*2^-4 = 2^(a*SEXPC - 4)

// ---------------------------------------------------------------------------
// R19: fusion v4. v3 (R18) SPILLED: FETCH 712 MB w/ WRITE 59 MB = spill-once,
// reload-per-iter (live set ~252 vs 256 cap: all 16 V loads held across S).
// Fix = R1's rolling-V register discipline on the v3 1-barrier schedule:
//   iter t: stage K(t+1) cp16 x8 (OLDEST in FIFO)
//           pa(t-1) ds_reads; V pairs 0..2 prefetch (24 regs, not 64)
//           S(t) 16 MFMA  ->  exp(t) -> P(t)
//           PV(t-1): pair c waits vmcnt(6,6,6,6,6,4,2,0); pairs 3..7 issued
//             rolling inside the loop; c=0's vmcnt(6) drains the cp16s free
//           lgkmcnt(0); barrier            (single barrier per iteration)
// Peak live ~216 (S) / ~208 (PV) < 256 @ (512,2). Math identical to v3
// (passed, absmax 0.03125). Tripwire: FETCH>100MB => fusion dead, revert R9.
// ---------------------------------------------------------------------------

typedef __bf16 bf16_t;
typedef __bf16 bf16x8 __attribute__((ext_vector_type(8)));
typedef float  f32x4  __attribute__((ext_vector_type(4)));
typedef int    i32x4  __attribute__((ext_vector_type(4)));
typedef int    i32x8  __attribute__((ext_vector_type(8)));
typedef unsigned int u32;
typedef __hip_fp8_e4m3 fp8_t;  // OCP e4m3fn on gfx950

// Async global->LDS copy, 16B per lane. LDS dest is wave-uniform base + lane*16.
__device__ __forceinline__ void cp16(const void* g, void* l) {
  __builtin_amdgcn_global_load_lds((__attribute__((address_space(1))) u32*)(g),
                                   (__attribute__((address_space(3))) u32*)(l),
                                   16, 0, 0);
}

// Raw v_exp_f32 (2^x). s_nop 1 covers the trans->consumer wait-state.
__device__ __forceinline__ float fexp2(float x) {
  float r;
  asm("v_exp_f32 %0, %1\n\ts_nop 1" : "=v"(r) : "v"(x));
  return r;
}

__device__ __forceinline__ void zero_acc(f32x4 acc[4][4]) {
  f32x4 z = {0.f, 0.f, 0.f, 0.f};
#pragma unroll
  for (int i = 0; i < 4; ++i)
#pragma unroll
    for (int j = 0; j < 4; ++j) acc[i][j] = z;
}

// MX-fp8 BT GEMM mainloop (BK=128), 128^2 tile — verified R12 structure.
template <bool ROWSUM, int SA = 0x7F, int SB = 0x7F>
__device__ __forceinline__ void gemm_bt_mx(const unsigned char* __restrict__ A,
                                           const unsigned char* __restrict__ B,
                                           int K, int lda, int ldb,
                                           f32x4 acc[4][4], f32x4 accl[4],
                                           unsigned char* AsB, unsigned char* BsB) {
  const int tid  = threadIdx.x;
  const int wave = tid >> 6;
  const int lane = tid & 63;
  const int wm = (wave >> 1) * 64;
  const int wn = (wave & 1) * 64;
  const int srow = lane >> 3;
  const int gch  = ((lane & 7) - srow) & 7;
  const unsigned char* gA = A + (size_t)(wave * 32 + srow) * lda + gch * 16;
  const unsigned char* gB = B + (size_t)(wave * 32 + srow) * ldb + gch * 16;
  const int lofs = wave * 32 * 128;
  const int fr = lane & 15;
  const int q  = lane >> 4;
  const int co0 = ((2 * q     + fr) & 7) * 16;
  const int co1 = ((2 * q + 1 + fr) & 7) * 16;
  const i32x8 vones = {0x38383838, 0x38383838, 0x38383838, 0x38383838,
                       0x38383838, 0x38383838, 0x38383838, 0x38383838};

  const int nT = K >> 7;
#pragma unroll
  for (int cc = 0; cc < 4; ++cc) {
    cp16(gA + (size_t)(cc * 8) * lda, AsB + lofs + cc * 1024);
    cp16(gB + (size_t)(cc * 8) * ldb, BsB + lofs + cc * 1024);
  }
  gA += 128; gB += 128;

#pragma unroll 1
  for (int t = 0; t < nT; ++t) {
    const int cur = t & 1;
    if (t + 1 < nT) {
#pragma unroll
      for (int cc = 0; cc < 4; ++cc) {
        cp16(gA + (size_t)(cc * 8) * lda, AsB + (cur ^ 1) * 16384 + lofs + cc * 1024);
        cp16(gB + (size_t)(cc * 8) * ldb, BsB + (cur ^ 1) * 16384 + lofs + cc * 1024);
      }
      gA += 128; gB += 128;
      asm volatile("s_waitcnt vmcnt(8)" ::: "memory");
    } else {
      asm volatile("s_waitcnt vmcnt(0)" ::: "memory");
    }
    __builtin_amdgcn_s_barrier();

    i32x8 a[4], b[4];
    const unsigned char* Ab = AsB + cur * 16384;
    const unsigned char* Bb = BsB + cur * 16384;
#pragma unroll
    for (int i = 0; i < 4; ++i) {
      const int ro = (wm + i * 16 + fr) * 128;
      i32x4 lo = *(const i32x4*)(Ab + ro + co0);
      i32x4 hi = *(const i32x4*)(Ab + ro + co1);
      a[i] = __builtin_shufflevector(lo, hi, 0, 1, 2, 3, 4, 5, 6, 7);
    }
#pragma unroll
    for (int j = 0; j < 4; ++j) {
      const int ro = (wn + j * 16 + fr) * 128;
      i32x4 lo = *(const i32x4*)(Bb + ro + co0);
      i32x4 hi = *(const i32x4*)(Bb + ro + co1);
      b[j] = __builtin_shufflevector(lo, hi, 0, 1, 2, 3, 4, 5, 6, 7);
    }
    __builtin_amdgcn_s_setprio(1);
#pragma unroll
    for (int i = 0; i < 4; ++i) {
#pragma unroll
      for (int j = 0; j < 4; ++j)
        acc[i][j] = __builtin_amdgcn_mfma_scale_f32_16x16x128_f8f6f4(
            a[i], b[j], acc[i][j], 0, 0, 0, SA, 0, SB);
      if (ROWSUM)
        accl[i] = __builtin_amdgcn_mfma_scale_f32_16x16x128_f8f6f4(
            a[i], vones, accl[i], 0, 0, 0, SA, 0, 0x7F);
    }
    __builtin_amdgcn_s_setprio(0);
    __builtin_amdgcn_s_barrier();
  }
}

// ---------------- prep: GroupNorm partials + weight casts (merged) ----------

__global__ void __launch_bounds__(256) prep_kernel(const float* __restrict__ x,
                                                   float* __restrict__ stats,
                                                   const float* __restrict__ qkv_w,
                                                   const float* __restrict__ proj_w,
                                                   fp8_t* __restrict__ wqkv8,
                                                   fp8_t* __restrict__ wproj8) {
  __shared__ float rs[256], rss[256];
  const int n = blockIdx.x;
  if (n < 1024) {
    const int bg = n >> 3;       // group id 0..127
    const int ch = n & 7;        // hw chunk 0..7
    const float4* base = (const float4*)(x + (size_t)bg * (CPG_ * HW_)) +
                         (size_t)ch * (CPG_ * HW_ / 4 / 8);
    float s = 0.f, ss = 0.f;
    for (int i = threadIdx.x; i < CPG_ * HW_ / 4 / 8; i += 256) {
      float4 v = base[i];
      s  += v.x + v.y + v.z + v.w;
      ss += v.x * v.x + v.y * v.y + v.z * v.z + v.w * v.w;
    }
    rs[threadIdx.x] = s; rss[threadIdx.x] = ss;
    __syncthreads();
    for (int st = 128; st > 0; st >>= 1) {
      if ((int)threadIdx.x < st) {
        rs[threadIdx.x]  += rs[threadIdx.x + st];
        rss[threadIdx.x] += rss[threadIdx.x + st];
      }
      __syncthreads();
    }
    if (threadIdx.x == 0) {
      stats[(bg * 8 + ch) * 2 + 0] = rs[0];
      stats[(bg * 8 + ch) * 2 + 1] = rss[0];
    }
  } else {
    const int idx = (n - 1024) * 256 + threadIdx.x;   // quad index
    const int t = idx * 4;
    const int nq = 1536 * 512;
    if (t < nq) {
      u32 dw = 0;
      dw = (u32)__builtin_amdgcn_cvt_pk_fp8_f32(qkv_w[t] * 16.f, qkv_w[t + 1] * 16.f, (int)dw, false);
      dw = (u32)__builtin_amdgcn_cvt_pk_fp8_f32(qkv_w[t + 2] * 16.f, qkv_w[t + 3] * 16.f, (int)dw, true);
      *(u32*)((unsigned char*)wqkv8 + t) = dw;
    } else {
      const int tt = t - nq;          // o*512 + p, p multiple of 4
      const int o = tt >> 9;
      const int p = tt & 511;
      float v[4];
#pragma unroll
      for (int e = 0; e < 4; ++e) {
        const int pe = p + e;
        const int off = pe & 63;
        const int c = (pe & ~63) + ((off & 3) << 4) + (off >> 2);  // sigma(pe)
        v[e] = proj_w[(o << 9) + c] * 16.f;
      }
      u32 dw = 0;
      dw = (u32)__builtin_amdgcn_cvt_pk_fp8_f32(v[0], v[1], (int)dw, false);
      dw = (u32)__builtin_amdgcn_cvt_pk_fp8_f32(v[2], v[3], (int)dw, true);
      *(u32*)((unsigned char*)wproj8 + tt) = dw;
    }
  }
}

// normalize + transpose: x[b][c][i] (fp32) -> xnT8[b][i][c] (fp8, plain order)
__global__ void __launch_bounds__(256) norm_tr_kernel(const float* __restrict__ x,
                                                      const float* __restrict__ stats,
                                                      const float* __restrict__ nw,
                                                      const float* __restrict__ nb,
                                                      fp8_t* __restrict__ xnT8) {
  __shared__ float tile[64][65];   // [c_off][i_off]
  const int b  = blockIdx.z;
  const int i0 = blockIdx.x * 64;   // hw
  const int c0 = blockIdx.y * 64;   // channel
  const int tx = threadIdx.x & 63;
  const int ty = threadIdx.x >> 6;  // 0..3
  const int cbase = c0 + ty * 16;
  const int g = cbase >> 4;         // group const across r (16 channels per ty)
  const float inv = 1.f / (float)(CPG_ * HW_);
  float sum = 0.f, ssum = 0.f;
#pragma unroll
  for (int ch = 0; ch < 8; ++ch) {
    sum  += stats[((b * G_ + g) * 8 + ch) * 2 + 0];
    ssum += stats[((b * G_ + g) * 8 + ch) * 2 + 1];
  }
  const float mean = sum * inv;
  const float rstd = rsqrtf(ssum * inv - mean * mean + EPS_);
#pragma unroll
  for (int r = 0; r < 16; ++r) {
    const int c = cbase + r;
    float v = x[((size_t)b * C_ + c) * HW_ + i0 + tx];
    tile[ty * 16 + r][tx] = (v - mean) * rstd * nw[c] + nb[c];
  }
  __syncthreads();
  const int il = threadIdx.x >> 2;
  const int q4 = threadIdx.x & 3;
#pragma unroll
  for (int m = 0; m < 4; ++m) {
    const int cq = q4 + m * 4;     // 0..15
    u32 dw = 0;
    dw = (u32)__builtin_amdgcn_cvt_pk_fp8_f32(tile[cq * 4 + 0][il], tile[cq * 4 + 1][il], (int)dw, false);
    dw = (u32)__builtin_amdgcn_cvt_pk_fp8_f32(tile[cq * 4 + 2][il], tile[cq * 4 + 3][il], (int)dw, true);
    *(u32*)((unsigned char*)xnT8 + ((size_t)b * HW_ + i0 + il) * C_ + c0 + cq * 4) = dw;
  }
}

// ---------------- GEMM kernels ----------------

// Merged qk+v projections.
__global__ void __launch_bounds__(256) qkv_gemm_kernel(const fp8_t* __restrict__ xnT8,
                                                       const fp8_t* __restrict__ wqkv8,
                                                       const float* __restrict__ qkv_b,
                                                       fp8_t* __restrict__ QKt8,
                                                       fp8_t* __restrict__ V8) {
  __shared__ __align__(16) unsigned char As[2 * 16384];
  __shared__ __align__(16) unsigned char Bs[2 * 16384];
  const int n = blockIdx.x;
  const int lane = threadIdx.x & 63, wave = threadIdx.x >> 6;
  const int wm = (wave >> 1) * 64, wn = (wave & 1) * 64;
  const int fr = lane & 15, q = lane >> 4;
  f32x4 acc[4][4]; zero_acc(acc);

  if (n < 1024) {
    const int xb = n & 7, yb = (n >> 3) & 31, b = n >> 8;
    const unsigned char* A  = (const unsigned char*)xnT8 + ((size_t)b * HW_ + yb * 128) * C_;
    const unsigned char* Bp = (const unsigned char*)wqkv8 + (size_t)xb * 128 * C_;
    gemm_bt_mx<false, 0x7F, 0x7B>(A, Bp, C_, C_, C_, acc, nullptr, As, Bs);
    const int r0 = yb * 128 + wm + (q << 2);
    const int cb = xb * 128 + wn;
    float bias[4];
#pragma unroll
    for (int j = 0; j < 4; ++j) bias[j] = qkv_b[cb + fr + j * 16];
#pragma unroll
    for (int i = 0; i < 4; ++i)
#pragma unroll
      for (int r = 0; r < 4; ++r) {
        const int row = r0 + i * 16 + r;
        u32 dw = 0;
        dw = (u32)__builtin_amdgcn_cvt_pk_fp8_f32(acc[i][0][r] + bias[0],
                                                  acc[i][1][r] + bias[1], (int)dw, false);
        dw = (u32)__builtin_amdgcn_cvt_pk_fp8_f32(acc[i][2][r] + bias[2],
                                                  acc[i][3][r] + bias[3], (int)dw, true);
        *(u32*)((unsigned char*)QKt8 + ((size_t)b * HW_ + row) * 1024 + cb + fr * 4) = dw;
      }
  } else {
    const int m = n - 1024;
    const int xb = m & 31, yb = (m >> 5) & 3, b = m >> 7;
    const unsigned char* A  = (const unsigned char*)wqkv8 + (size_t)(1024 + yb * 128) * C_;
    const unsigned char* Bp = (const unsigned char*)xnT8 + ((size_t)b * HW_ + xb * 128) * C_;
    gemm_bt_mx<false, 0x7B, 0x7F>(A, Bp, C_, C_, C_, acc, nullptr, As, Bs);
    const int r0 = yb * 128 + wm + (q << 2);
    const int cb = xb * 128 + wn;
#pragma unroll
    for (int i = 0; i < 4; ++i)
#pragma unroll
      for (int r = 0; r < 4; ++r) {
        const int row = r0 + i * 16 + r;        // c channel (row of V8)
        const float bias = qkv_b[1024 + row];
        u32 dw = 0;
        dw = (u32)__builtin_amdgcn_cvt_pk_fp8_f32(acc[i][0][r] + bias,
                                                  acc[i][1][r] + bias, (int)dw, false);
        dw = (u32)__builtin_amdgcn_cvt_pk_fp8_f32(acc[i][2][r] + bias,
                                                  acc[i][3][r] + bias, (int)dw, true);
        *(u32*)((unsigned char*)V8 + ((size_t)b * C_ + row) * HW_ + cb + fr * 4) = dw;
      }
  }
}

// ---------------------------------------------------------------------------
// Fused attention v4: hmT8 = fp8(16 * (exp(s*QK^T) . V) / rowsum), P never
// touches global. 256 blocks (4 batches x 64-row Q panels), 8 waves.
//   wave: ih = w&1 (32-row half), jq = w>>1 (S col quarter / PV ch group cg).
// Schedule per iter (1 barrier, rolling V): see file header.
// LDS: K dbuf 2x64KB + P dbuf 2x8KB = 144 KB.
// ---------------------------------------------------------------------------
__global__ void __launch_bounds__(512, 2)
fused_attn_kernel(const fp8_t* __restrict__ QKt8, const fp8_t* __restrict__ V8,
                  fp8_t* __restrict__ hmT8) {
  __shared__ __align__(16) unsigned char kbuf[2][65536];
  __shared__ __align__(16) unsigned char pbuf[2][8192];

  // XCD decode (R1-verified L2 behavior): batch b -> XCDs {2b, 2b+1}
  const int n     = blockIdx.x;
  const int xcd   = n & 7;
  const int b     = xcd >> 1;
  const int panel = (xcd & 1) * 32 + (n >> 3);   // 0..63

  const int tid  = threadIdx.x;
  const int lane = tid & 63;
  const int wave = tid >> 6;
  const int fr   = lane & 15;
  const int q    = lane >> 4;
  const int ih   = wave & 1;
  const int jq   = wave >> 1;
  const int cg   = wave >> 1;

  const unsigned char* QKb = (const unsigned char*)QKt8 + (size_t)b * HW_ * 1024;
  const unsigned char* gK  = QKb + 512;   // K half of qkv columns

  const int sch = tid & 31;   // staging chunk within a 512-B row
  const int srw = tid >> 5;   // staging row within a 16-row pass

  // ---- prologue: stage Q (64x512) into kbuf[0], preload qf ----
#pragma unroll
  for (int p = 0; p < 4; ++p) {
    const int row = p * 16 + srw;
    cp16(QKb + (size_t)(panel * 64 + row) * 1024 + (((sch - row) & 31) << 4),
         kbuf[0] + row * 512 + sch * 16);
  }
  asm volatile("s_waitcnt vmcnt(0)" ::: "memory");
  __builtin_amdgcn_s_barrier();

  i32x8 qf[2][4];
#pragma unroll
  for (int ii = 0; ii < 2; ++ii) {
    const int row = ih * 32 + ii * 16 + fr;
    const unsigned char* qr = kbuf[0] + row * 512;
#pragma unroll
    for (int k = 0; k < 4; ++k) {
      i32x4 lo = *(const i32x4*)(qr + (((k * 8 + 2 * q + row) & 31) << 4));
      i32x4 hi = *(const i32x4*)(qr + (((k * 8 + 2 * q + 1 + row) & 31) << 4));
      qf[ii][k] = __builtin_shufflevector(lo, hi, 0, 1, 2, 3, 4, 5, 6, 7);
    }
  }
  asm volatile("s_waitcnt lgkmcnt(0)" ::: "memory");
  __builtin_amdgcn_s_barrier();   // all waves done reading Q region

  // ---- stage K(0) into kbuf[0] ----
#pragma unroll
  for (int p = 0; p < 8; ++p) {
    const int row = p * 16 + srw;
    cp16(gK + (size_t)row * 1024 + (((sch - row) & 31) << 4),
         kbuf[0] + row * 512 + sch * 16);
  }

  f32x4 pvacc[2][8];
  f32x4 accl[2];
  {
    f32x4 z = {0.f, 0.f, 0.f, 0.f};
#pragma unroll
    for (int i = 0; i < 2; ++i) {
#pragma unroll
      for (int j = 0; j < 8; ++j) pvacc[i][j] = z;
      accl[i] = z;
    }
  }
  const i32x8 vones = {0x38383838, 0x38383838, 0x38383838, 0x38383838,
                       0x38383838, 0x38383838, 0x38383838, 0x38383838};

  const unsigned char* vbase = (const unsigned char*)V8 +
      ((size_t)b * C_ + cg * 128 + fr) * HW_ + q * 32;

  const int kr0 = jq * 32 + fr;
  const int kr1 = kr0 + 16;
  const int offb = (jq >> 1) * 64 + fr * 4 + (jq & 1) * 2;  // P stored byte pos

  // S-phase macro pieces (R1-verified formulas)
#define S_PHASE(KB, SA0, SA1)                                                  \
  {                                                                            \
    const unsigned char* k0p = (KB) + kr0 * 512;                               \
    const unsigned char* k1p = (KB) + kr1 * 512;                               \
    _Pragma("unroll")                                                          \
    for (int k = 0; k < 4; ++k) {                                              \
      i32x4 l0 = *(const i32x4*)(k0p + (((k * 8 + 2 * q + kr0) & 31) << 4));   \
      i32x4 h0 = *(const i32x4*)(k0p + (((k * 8 + 2 * q + 1 + kr0) & 31) << 4));\
      i32x4 l1 = *(const i32x4*)(k1p + (((k * 8 + 2 * q + kr1) & 31) << 4));   \
      i32x4 h1 = *(const i32x4*)(k1p + (((k * 8 + 2 * q + 1 + kr1) & 31) << 4));\
      i32x8 kf0 = __builtin_shufflevector(l0, h0, 0, 1, 2, 3, 4, 5, 6, 7);     \
      i32x8 kf1 = __builtin_shufflevector(l1, h1, 0, 1, 2, 3, 4, 5, 6, 7);     \
      _Pragma("unroll")                                                        \
      for (int ii = 0; ii < 2; ++ii) {                                         \
        SA0[ii] = __builtin_amdgcn_mfma_scale_f32_16x16x128_f8f6f4(            \
            qf[ii][k], kf0, SA0[ii], 0, 0, 0, 0x7F, 0, 0x7F);                  \
        SA1[ii] = __builtin_amdgcn_mfma_scale_f32_16x16x128_f8f6f4(            \
            qf[ii][k], kf1, SA1[ii], 0, 0, 0, 0x7F, 0, 0x7F);                  \
      }                                                                        \
    }                                                                          \
  }

#define EXP_TO_P(PB, SA0, SA1)                                                 \
  {                                                                            \
    _Pragma("unroll")                                                          \
    for (int ii = 0; ii < 2; ++ii)                                             \
      _Pragma("unroll")                                                        \
      for (int r = 0; r < 4; ++r) {                                            \
        const int row = ih * 32 + ii * 16 + q * 4 + r;                         \
        float e0 = fexp2(fmaf(SA0[ii][r], SEXPC_, -4.0f));                     \
        float e1 = fexp2(fmaf(SA1[ii][r], SEXPC_, -4.0f));                     \
        u32 dw = (u32)__builtin_amdgcn_cvt_pk_fp8_f32(e0, e1, 0, false);       \
        *(unsigned short*)((PB) + row * 128 + ((((offb >> 4) + row) & 7) << 4) \
                           + (offb & 15)) = (unsigned short)dw;                \
      }                                                                        \
  }

  // ---- peel t = 0: S(0) + exp(0) -> pbuf[0]; stage K(1) ----
  {
    asm volatile("s_waitcnt vmcnt(0)" ::: "memory");  // K(0) resident
    __builtin_amdgcn_s_barrier();
    f32x4 s0[2], s1[2];
    {
      f32x4 z = {0.f, 0.f, 0.f, 0.f};
      s0[0] = z; s0[1] = z; s1[0] = z; s1[1] = z;
    }
    S_PHASE(kbuf[0], s0, s1)
#pragma unroll
    for (int p = 0; p < 8; ++p) {
      const int row = p * 16 + srw;
      cp16(gK + (size_t)(128 + row) * 1024 + (((sch - row) & 31) << 4),
           kbuf[1] + row * 512 + sch * 16);
    }
    EXP_TO_P(pbuf[0], s0, s1)
    asm volatile("s_waitcnt lgkmcnt(0) vmcnt(0)" ::: "memory");
    __builtin_amdgcn_s_barrier();   // P(0) visible, K(1) resident
  }

  // ---- main loop t = 1..31: S(t) || PV(t-1), rolling V ----
#pragma unroll 1
  for (int t = 1; t < 32; ++t) {
    const unsigned char* kb = kbuf[t & 1];          // K(t)
    const unsigned char* pb = pbuf[(t & 1) ^ 1];    // P(t-1)
    unsigned char* pw = pbuf[t & 1];                // P(t) dest

    // stage K(t+1) FIRST (oldest in vmem FIFO; drained free by PV's vmcnt(6))
    if (t < 31) {
#pragma unroll
      for (int p = 0; p < 8; ++p) {
        const int row = p * 16 + srw;
        cp16(gK + (size_t)((t + 1) * 128 + row) * 1024 + (((sch - row) & 31) << 4),
             kbuf[(t + 1) & 1] + row * 512 + sch * 16);
      }
    }

    // pa(t-1) LDS reads
    i32x8 pa[2];
#pragma unroll
    for (int ii = 0; ii < 2; ++ii) {
      const int prow = ih * 32 + ii * 16 + fr;
      const unsigned char* pp = pb + prow * 128;
      i32x4 lo = *(const i32x4*)(pp + (((2 * q + prow) & 7) << 4));
      i32x4 hi = *(const i32x4*)(pp + (((2 * q + 1 + prow) & 7) << 4));
      pa[ii] = __builtin_shufflevector(lo, hi, 0, 1, 2, 3, 4, 5, 6, 7);
    }

    // V(t-1) prefetch: pairs 0..2 only (24 regs live across S, not 64)
    const unsigned char* vp = vbase + (size_t)(t - 1) * 128;
    i32x4 vl[8], vh[8];
#pragma unroll
    for (int c = 0; c < 3; ++c) {
      vl[c] = *(const i32x4*)(vp + (size_t)(c * 16) * HW_);
      vh[c] = *(const i32x4*)(vp + (size_t)(c * 16) * HW_ + 16);
    }

    // S(t)
    f32x4 s0[2], s1[2];
    {
      f32x4 z = {0.f, 0.f, 0.f, 0.f};
      s0[0] = z; s0[1] = z; s1[0] = z; s1[1] = z;
    }
    __builtin_amdgcn_s_setprio(1);
    S_PHASE(kb, s0, s1)
    __builtin_amdgcn_s_setprio(0);

    // exp(t) -> P(t)
    EXP_TO_P(pw, s0, s1)

    // PV(t-1): rolling V pairs 3..7 issued in-loop; counted vmcnt per pair.
    // FIFO at pair c: [8 cp16][pairs 0..2][pairs 3..c+3]; vmcnt leaves the
    // 3 following pairs in flight (6,6,6,6,6,4,2,0).
    __builtin_amdgcn_s_setprio(1);
#pragma unroll
    for (int c = 0; c < 8; ++c) {
      if (c < 5) {
        vl[c + 3] = *(const i32x4*)(vp + (size_t)((c + 3) * 16) * HW_);
        vh[c + 3] = *(const i32x4*)(vp + (size_t)((c + 3) * 16) * HW_ + 16);
      }
      if (c < 5)       asm volatile("s_waitcnt vmcnt(6)" ::: "memory");
      else if (c == 5) asm volatile("s_waitcnt vmcnt(4)" ::: "memory");
      else if (c == 6) asm volatile("s_waitcnt vmcnt(2)" ::: "memory");
      else             asm volatile("s_waitcnt vmcnt(0)" ::: "memory");
      i32x8 v = __builtin_shufflevector(vl[c], vh[c], 0, 1, 2, 3, 4, 5, 6, 7);
      pvacc[0][c] = __builtin_amdgcn_mfma_scale_f32_16x16x128_f8f6f4(
          pa[0], v, pvacc[0][c], 0, 0, 0, 0x7F, 0, 0x7F);
      pvacc[1][c] = __builtin_amdgcn_mfma_scale_f32_16x16x128_f8f6f4(
          pa[1], v, pvacc[1][c], 0, 0, 0, 0x7F, 0, 0x7F);
    }
    accl[0] = __builtin_amdgcn_mfma_scale_f32_16x16x128_f8f6f4(
        pa[0], vones, accl[0], 0, 0, 0, 0x7F, 0, 0x7F);
    accl[1] = __builtin_amdgcn_mfma_scale_f32_16x16x128_f8f6f4(
        pa[1], vones, accl[1], 0, 0, 0, 0x7F, 0, 0x7F);
    __builtin_amdgcn_s_setprio(0);

    // P(t) writes + all ds reads drained; K(t+1) drained at c=0 -> 1 barrier
    asm volatile("s_waitcnt lgkmcnt(0)" ::: "memory");
    __builtin_amdgcn_s_barrier();
  }

  // ---- epilogue PV(31) ----
  {
    const unsigned char* pb = pbuf[1];   // P(31), t=31 wrote pbuf[31&1]=1
    i32x8 pa[2];
#pragma unroll
    for (int ii = 0; ii < 2; ++ii) {
      const int prow = ih * 32 + ii * 16 + fr;
      const unsigned char* pp = pb + prow * 128;
      i32x4 lo = *(const i32x4*)(pp + (((2 * q + prow) & 7) << 4));
      i32x4 hi = *(const i32x4*)(pp + (((2 * q + 1 + prow) & 7) << 4));
      pa[ii] = __builtin_shufflevector(lo, hi, 0, 1, 2, 3, 4, 5, 6, 7);
    }
    const unsigned char* vp = vbase + (size_t)31 * 128;
#pragma unroll
    for (int c = 0; c < 8; ++c) {
      i32x4 vl = *(const i32x4*)(vp + (size_t)(c * 16) * HW_);
      i32x4 vh = *(const i32x4*)(vp + (size_t)(c * 16) * HW_ + 16);
      i32x8 v = __builtin_shufflevector(vl, vh, 0, 1, 2, 3, 4, 5, 6, 7);
      pvacc[0][c] = __builtin_amdgcn_mfma_scale_f32_16x16x128_f8f6f4(
          pa[0], v, pvacc[0][c], 0, 0, 0, 0x7F, 0, 0x7F);
      pvacc[1][c] = __builtin_amdgcn_mfma_scale_f32_16x16x128_f8f6f4(
          pa[1], v, pvacc[1][c], 0, 0, 0, 0x7F, 0, 0x7F);
    }
    accl[0] = __builtin_amdgcn_mfma_scale_f32_16x16x128_f8f6f4(
        pa[0], vones, accl[0], 0, 0, 0, 0x7F, 0, 0x7F);
    accl[1] = __builtin_amdgcn_mfma_scale_f32_16x16x128_f8f6f4(
        pa[1], vones, accl[1], 0, 0, 0, 0x7F, 0, 0x7F);
  }

  // ---- hmT8 epilogue (R1-verified store pattern) ----
  unsigned char* hb = (unsigned char*)hmT8 + (size_t)b * HW_ * C_;
#pragma unroll
  for (int ii = 0; ii < 2; ++ii)
#pragma unroll
    for (int r = 0; r < 4; ++r) {
      const int row = panel * 64 + ih * 32 + ii * 16 + q * 4 + r;
      const float rl = 16.f * __builtin_amdgcn_rcpf(accl[ii][r]);
#pragma unroll
      for (int g = 0; g < 2; ++g) {
        u32 dw = 0;
        dw = (u32)__builtin_amdgcn_cvt_pk_fp8_f32(pvacc[ii][g * 4 + 0][r] * rl,
                                                  pvacc[ii][g * 4 + 1][r] * rl, (int)dw, false);
        dw = (u32)__builtin_amdgcn_cvt_pk_fp8_f32(pvacc[ii][g * 4 + 2][r] * rl,
                                                  pvacc[ii][g * 4 + 3][r] * rl, (int)dw, true);
        *(u32*)(hb + (size_t)row * C_ + cg * 128 + g * 64 + fr * 4) = dw;
      }
    }
}

// out[b][o][i] = x[b][o][i] + proj_b[o] + (wproj8*2^-4)(sigma) . (hmT8*2^-4)(sigma)
__global__ void __launch_bounds__(256) proj_gemm_kernel(const fp8_t* __restrict__ wproj8,
                                                        const fp8_t* __restrict__ hmT8,
                                                        const float* __restrict__ proj_b,
                                                        const float* __restrict__ x,
                                                        float* __restrict__ out) {
  __shared__ __align__(16) unsigned char As[2 * 16384];
  __shared__ __align__(16) unsigned char Bs[2 * 16384];
  const int b = blockIdx.z;
  f32x4 acc[4][4]; zero_acc(acc);
  const unsigned char* A  = (const unsigned char*)wproj8 + (size_t)blockIdx.y * 128 * C_;
  const unsigned char* Bp = (const unsigned char*)hmT8 + ((size_t)b * HW_ + blockIdx.x * 128) * C_;
  gemm_bt_mx<false, 0x7B, 0x7B>(A, Bp, C_, C_, C_, acc, nullptr, As, Bs);
  const int lane = threadIdx.x & 63, wave = threadIdx.x >> 6;
  const int wm = (wave >> 1) * 64, wn = (wave & 1) * 64;
  const int r0 = blockIdx.y * 128 + wm + ((lane >> 4) << 2);
  const int c0 = blockIdx.x * 128 + wn + (lane & 15);
#pragma unroll
  for (int i = 0; i < 4; ++i)
#pragma unroll
    for (int r = 0; r < 4; ++r) {
      const int row = r0 + i * 16 + r;
      const float bias = proj_b[row];
#pragma unroll
      for (int j = 0; j < 4; ++j) {
        const int col = c0 + j * 16;
        const size_t idx = ((size_t)b * C_ + row) * HW_ + col;
        out[idx] = x[idx] + bias + acc[i][j][r];
      }
    }
}

// ---------------- launch ----------------
// Workspace layout (bytes), total ~43 MB (P8 not materialized):
//   wqkv8  fp8 [1536][512] (x16)         786,432
//   wproj8 fp8 [512][512] (x16, sigma)   262,144
//   stats  f32 [128][8][2]                 8,192
//   xnT8   fp8 [4][4096][512]          8,388,608
//   QKt8   fp8 [4][4096][1024](sig)   16,777,216
//   V8     fp8 [4][512][4096] (sig)    8,388,608
//   hmT8   fp8 [4][4096][512] (x16,sig) 8,388,608
extern "C" void kernel_launch(void* const* d_in, const int* in_sizes, int n_in,
                              void* d_out, int out_size, void* d_ws, size_t ws_size,
                              hipStream_t stream) {
  const float* x      = (const float*)d_in[0];
  const float* norm_w = (const float*)d_in[1];
  const float* norm_b = (const float*)d_in[2];
  const float* qkv_w  = (const float*)d_in[3];
  const float* qkv_b  = (const float*)d_in[4];
  const float* proj_w = (const float*)d_in[5];
  const float* proj_b = (const float*)d_in[6];
  float* out = (float*)d_out;

  char* ws = (char*)d_ws;
  size_t o = 0;
  fp8_t* wqkv8  = (fp8_t*)(ws + o); o += (size_t)1536 * 512;
  fp8_t* wproj8 = (fp8_t*)(ws + o); o += (size_t)512 * 512;
  float* stats  = (float*)(ws + o); o += 128 * 8 * 2 * 4;
  fp8_t* xnT8   = (fp8_t*)(ws + o); o += (size_t)B_ * HW_ * C_;
  fp8_t* QKt8   = (fp8_t*)(ws + o); o += (size_t)B_ * HW_ * 1024;
  fp8_t* V8     = (fp8_t*)(ws + o); o += (size_t)B_ * C_ * HW_;
  fp8_t* hmT8   = (fp8_t*)(ws + o); o += (size_t)B_ * HW_ * C_;

  prep_kernel<<<2048, 256, 0, stream>>>(x, stats, qkv_w, proj_w, wqkv8, wproj8);
  norm_tr_kernel<<<dim3(HW_ / 64, C_ / 64, B_), 256, 0, stream>>>(x, stats, norm_w, norm_b, xnT8);
  qkv_gemm_kernel<<<1536, 256, 0, stream>>>(xnT8, wqkv8, qkv_b, QKt8, V8);
  fused_attn_kernel<<<256, 512, 0, stream>>>(QKt8, V8, hmT8);
  proj_gemm_kernel<<<dim3(HW_ / 128, C_ / 128, B_), 256, 0, stream>>>(
      wproj8, hmT8, proj_b, x, out);
}

// Round 12
// 226.840 us; speedup vs baseline: 2.5088x; 1.4612x over previous
//
#include <hip/hip_runtime.h>
#include <hip/hip_fp8.h>
#include <cstdint>
#include <cmath>

// Problem constants
#define B_   4
#define C_   512
#define HW_  4096
#define G_   32
#define CPG_ 16
#define EPS_ 1e-6f
#define SCALE_ 0.04419417382415922f  // 1/sqrt(512)
#define PSCALE_ 0.0625f              // P pre-scale; cancels in acc/rowsum ratio
#define SEXPC_ 0.063758715306f       // SCALE * log2(e): exp(a*S)*2^-4 = 2^(a*SEXPC - 4)

// ---------------------------------------------------------------------------
// R20: FINAL — revert to the R17/R9 configuration (227.7 us, session best).
// Fusion arc closed by arithmetic: fused MFMA demand 31 us@100% vs unfused
// 33 us; beating the unfused 100 us (sexp+pv) needs >31% MfmaUtil, above the
// ~24% latency-rotation ceiling every structure hit in this session (six
// GEMM schedules, four fusion schedules; v4 fixed the spill, still 200 us
// @14.6%). Not a HW roofline (24% MFMA / 18% HBM), but the practical floor
// of source-level scheduling for these shapes.
// Pipeline: prep(GN partials + w-cast, atomic-free) -> norm_tr -> qkv(merged)
// -> sexp (exp2-fold epilogue, XCD map) -> pv (rowsum via ones-MFMA, rcp,
// reverse within-XCD order for P L2 heat) -> proj (+x residual).
// ---------------------------------------------------------------------------

typedef __bf16 bf16_t;
typedef __bf16 bf16x8 __attribute__((ext_vector_type(8)));
typedef float  f32x4  __attribute__((ext_vector_type(4)));
typedef int    i32x4  __attribute__((ext_vector_type(4)));
typedef int    i32x8  __attribute__((ext_vector_type(8)));
typedef unsigned int u32;
typedef __hip_fp8_e4m3 fp8_t;  // OCP e4m3fn on gfx950

// Async global->LDS copy, 16B per lane. LDS dest is wave-uniform base + lane*16.
__device__ __forceinline__ void cp16(const void* g, void* l) {
  __builtin_amdgcn_global_load_lds((__attribute__((address_space(1))) u32*)(g),
                                   (__attribute__((address_space(3))) u32*)(l),
                                   16, 0, 0);
}

// Raw v_exp_f32 (2^x). s_nop 1 covers the trans->consumer wait-state
// conservatively (inline asm is opaque to the hazard recognizer).
__device__ __forceinline__ float fexp2(float x) {
  float r;
  asm("v_exp_f32 %0, %1\n\ts_nop 1" : "=v"(r) : "v"(x));
  return r;
}

__device__ __forceinline__ void zero_acc(f32x4 acc[4][4]) {
  f32x4 z = {0.f, 0.f, 0.f, 0.f};
#pragma unroll
  for (int i = 0; i < 4; ++i)
#pragma unroll
    for (int j = 0; j < 4; ++j) acc[i][j] = z;
}

// MX-fp8 BT GEMM mainloop (BK=128): mfma_scale_f32_16x16x128_f8f6f4, fmt 0
// (e4m3), per-operand e8m0 scales SA/SB (0x7F = 1.0, 0x7B = 2^-4).
// LDS rows are 128 B (8 chunks); chunk-rotation swizzle mod 8 keeps staging
// and the paired ds_read_b128 fragment reads at the LDS bank floor.
// Double-buffered (2x16 KB per operand, caller-provided LDS), counted vmcnt.
template <bool ROWSUM, int SA = 0x7F, int SB = 0x7F>
__device__ __forceinline__ void gemm_bt_mx(const unsigned char* __restrict__ A,
                                           const unsigned char* __restrict__ B,
                                           int K, int lda, int ldb,
                                           f32x4 acc[4][4], f32x4 accl[4],
                                           unsigned char* AsB, unsigned char* BsB) {
  const int tid  = threadIdx.x;
  const int wave = tid >> 6;
  const int lane = tid & 63;
  const int wm = (wave >> 1) * 64;
  const int wn = (wave & 1) * 64;
  // staging: per cp16 call lane covers row (lane>>3), LDS chunk (lane&7);
  // rotation: LDS chunk c of row r holds global chunk (c - r) & 7.
  const int srow = lane >> 3;
  const int gch  = ((lane & 7) - srow) & 7;
  const unsigned char* gA = A + (size_t)(wave * 32 + srow) * lda + gch * 16;
  const unsigned char* gB = B + (size_t)(wave * 32 + srow) * ldb + gch * 16;
  const int lofs = wave * 32 * 128;
  const int fr = lane & 15;
  const int q  = lane >> 4;
  // lane wants global chunks 2q, 2q+1 of its row (32 B = K-128 fragment)
  const int co0 = ((2 * q     + fr) & 7) * 16;
  const int co1 = ((2 * q + 1 + fr) & 7) * 16;
  const i32x8 vones = {0x38383838, 0x38383838, 0x38383838, 0x38383838,
                       0x38383838, 0x38383838, 0x38383838, 0x38383838};

  const int nT = K >> 7;
  // prologue: stage tile 0 into buffer 0
#pragma unroll
  for (int cc = 0; cc < 4; ++cc) {
    cp16(gA + (size_t)(cc * 8) * lda, AsB + lofs + cc * 1024);
    cp16(gB + (size_t)(cc * 8) * ldb, BsB + lofs + cc * 1024);
  }
  gA += 128; gB += 128;

#pragma unroll 1
  for (int t = 0; t < nT; ++t) {
    const int cur = t & 1;
    if (t + 1 < nT) {
      // stage tile t+1 into the other buffer; it flies across this tile's
      // compute and is drained by next iteration's vmcnt(8).
#pragma unroll
      for (int cc = 0; cc < 4; ++cc) {
        cp16(gA + (size_t)(cc * 8) * lda, AsB + (cur ^ 1) * 16384 + lofs + cc * 1024);
        cp16(gB + (size_t)(cc * 8) * ldb, BsB + (cur ^ 1) * 16384 + lofs + cc * 1024);
      }
      gA += 128; gB += 128;
      asm volatile("s_waitcnt vmcnt(8)" ::: "memory");  // tile t resident
    } else {
      asm volatile("s_waitcnt vmcnt(0)" ::: "memory");  // last tile resident
    }
    __builtin_amdgcn_s_barrier();   // tile t visible to all waves

    i32x8 a[4], b[4];
    const unsigned char* Ab = AsB + cur * 16384;
    const unsigned char* Bb = BsB + cur * 16384;
#pragma unroll
    for (int i = 0; i < 4; ++i) {
      const int ro = (wm + i * 16 + fr) * 128;
      i32x4 lo = *(const i32x4*)(Ab + ro + co0);
      i32x4 hi = *(const i32x4*)(Ab + ro + co1);
      a[i] = __builtin_shufflevector(lo, hi, 0, 1, 2, 3, 4, 5, 6, 7);
    }
#pragma unroll
    for (int j = 0; j < 4; ++j) {
      const int ro = (wn + j * 16 + fr) * 128;
      i32x4 lo = *(const i32x4*)(Bb + ro + co0);
      i32x4 hi = *(const i32x4*)(Bb + ro + co1);
      b[j] = __builtin_shufflevector(lo, hi, 0, 1, 2, 3, 4, 5, 6, 7);
    }
    __builtin_amdgcn_s_setprio(1);
#pragma unroll
    for (int i = 0; i < 4; ++i) {
#pragma unroll
      for (int j = 0; j < 4; ++j)
        acc[i][j] = __builtin_amdgcn_mfma_scale_f32_16x16x128_f8f6f4(
            a[i], b[j], acc[i][j], 0, 0, 0, SA, 0, SB);
      if (ROWSUM)
        accl[i] = __builtin_amdgcn_mfma_scale_f32_16x16x128_f8f6f4(
            a[i], vones, accl[i], 0, 0, 0, SA, 0, 0x7F);
    }
    __builtin_amdgcn_s_setprio(0);
    __builtin_amdgcn_s_barrier();   // all reads of buf[cur] done
  }
}

// ---------------- prep: GroupNorm partials + weight casts (merged) ----------

// blocks [0,1024): partial GN stats -> stats[bg][ch][2] (atomic-free; every
// slot written, so no memset needed).
// blocks [1024,2048): wqkv8 = fp8(qkv_w*16) plain; wproj8 = fp8(proj_w*16)
// with sigma-permuted c columns.
__global__ void __launch_bounds__(256) prep_kernel(const float* __restrict__ x,
                                                   float* __restrict__ stats,
                                                   const float* __restrict__ qkv_w,
                                                   const float* __restrict__ proj_w,
                                                   fp8_t* __restrict__ wqkv8,
                                                   fp8_t* __restrict__ wproj8) {
  __shared__ float rs[256], rss[256];
  const int n = blockIdx.x;
  if (n < 1024) {
    const int bg = n >> 3;       // group id 0..127
    const int ch = n & 7;        // hw chunk 0..7
    const float4* base = (const float4*)(x + (size_t)bg * (CPG_ * HW_)) +
                         (size_t)ch * (CPG_ * HW_ / 4 / 8);
    float s = 0.f, ss = 0.f;
    for (int i = threadIdx.x; i < CPG_ * HW_ / 4 / 8; i += 256) {
      float4 v = base[i];
      s  += v.x + v.y + v.z + v.w;
      ss += v.x * v.x + v.y * v.y + v.z * v.z + v.w * v.w;
    }
    rs[threadIdx.x] = s; rss[threadIdx.x] = ss;
    __syncthreads();
    for (int st = 128; st > 0; st >>= 1) {
      if ((int)threadIdx.x < st) {
        rs[threadIdx.x]  += rs[threadIdx.x + st];
        rss[threadIdx.x] += rss[threadIdx.x + st];
      }
      __syncthreads();
    }
    if (threadIdx.x == 0) {
      stats[(bg * 8 + ch) * 2 + 0] = rs[0];
      stats[(bg * 8 + ch) * 2 + 1] = rss[0];
    }
  } else {
    const int idx = (n - 1024) * 256 + threadIdx.x;   // quad index
    const int t = idx * 4;
    const int nq = 1536 * 512;
    if (t < nq) {
      u32 dw = 0;
      dw = (u32)__builtin_amdgcn_cvt_pk_fp8_f32(qkv_w[t] * 16.f, qkv_w[t + 1] * 16.f, (int)dw, false);
      dw = (u32)__builtin_amdgcn_cvt_pk_fp8_f32(qkv_w[t + 2] * 16.f, qkv_w[t + 3] * 16.f, (int)dw, true);
      *(u32*)((unsigned char*)wqkv8 + t) = dw;
    } else {
      const int tt = t - nq;          // o*512 + p, p multiple of 4
      const int o = tt >> 9;
      const int p = tt & 511;
      float v[4];
#pragma unroll
      for (int e = 0; e < 4; ++e) {
        const int pe = p + e;
        const int off = pe & 63;
        const int c = (pe & ~63) + ((off & 3) << 4) + (off >> 2);  // sigma(pe)
        v[e] = proj_w[(o << 9) + c] * 16.f;
      }
      u32 dw = 0;
      dw = (u32)__builtin_amdgcn_cvt_pk_fp8_f32(v[0], v[1], (int)dw, false);
      dw = (u32)__builtin_amdgcn_cvt_pk_fp8_f32(v[2], v[3], (int)dw, true);
      *(u32*)((unsigned char*)wproj8 + tt) = dw;
    }
  }
}

// normalize + transpose: x[b][c][i] (fp32) -> xnT8[b][i][c] (fp8, plain order)
// Reduces the 8 per-chunk stat partials inline (deterministic order).
__global__ void __launch_bounds__(256) norm_tr_kernel(const float* __restrict__ x,
                                                      const float* __restrict__ stats,
                                                      const float* __restrict__ nw,
                                                      const float* __restrict__ nb,
                                                      fp8_t* __restrict__ xnT8) {
  __shared__ float tile[64][65];   // [c_off][i_off]
  const int b  = blockIdx.z;
  const int i0 = blockIdx.x * 64;   // hw
  const int c0 = blockIdx.y * 64;   // channel
  const int tx = threadIdx.x & 63;
  const int ty = threadIdx.x >> 6;  // 0..3
  const int cbase = c0 + ty * 16;
  const int g = cbase >> 4;         // group const across r (16 channels per ty)
  const float inv = 1.f / (float)(CPG_ * HW_);
  float sum = 0.f, ssum = 0.f;
#pragma unroll
  for (int ch = 0; ch < 8; ++ch) {
    sum  += stats[((b * G_ + g) * 8 + ch) * 2 + 0];
    ssum += stats[((b * G_ + g) * 8 + ch) * 2 + 1];
  }
  const float mean = sum * inv;
  const float rstd = rsqrtf(ssum * inv - mean * mean + EPS_);
#pragma unroll
  for (int r = 0; r < 16; ++r) {
    const int c = cbase + r;
    float v = x[((size_t)b * C_ + c) * HW_ + i0 + tx];
    tile[ty * 16 + r][tx] = (v - mean) * rstd * nw[c] + nb[c];
  }
  __syncthreads();
  const int il = threadIdx.x >> 2;
  const int q4 = threadIdx.x & 3;
#pragma unroll
  for (int m = 0; m < 4; ++m) {
    const int cq = q4 + m * 4;     // 0..15
    u32 dw = 0;
    dw = (u32)__builtin_amdgcn_cvt_pk_fp8_f32(tile[cq * 4 + 0][il], tile[cq * 4 + 1][il], (int)dw, false);
    dw = (u32)__builtin_amdgcn_cvt_pk_fp8_f32(tile[cq * 4 + 2][il], tile[cq * 4 + 3][il], (int)dw, true);
    *(u32*)((unsigned char*)xnT8 + ((size_t)b * HW_ + i0 + il) * C_ + c0 + cq * 4) = dw;
  }
}

// ---------------- GEMM kernels ----------------

// Merged qk+v projections (saves a dispatch; v's small grid rides qk's tail).
// blocks [0,1024): QKt8[b][i][sig o] = fp8( xnT8 . wqkv8*2^-4 + bias )
// blocks [1024,1536): V8[b][c][sig j] = fp8( wqkv8_v*2^-4 . xnT8 + bias )
__global__ void __launch_bounds__(256) qkv_gemm_kernel(const fp8_t* __restrict__ xnT8,
                                                       const fp8_t* __restrict__ wqkv8,
                                                       const float* __restrict__ qkv_b,
                                                       fp8_t* __restrict__ QKt8,
                                                       fp8_t* __restrict__ V8) {
  __shared__ __align__(16) unsigned char As[2 * 16384];
  __shared__ __align__(16) unsigned char Bs[2 * 16384];
  const int n = blockIdx.x;
  const int lane = threadIdx.x & 63, wave = threadIdx.x >> 6;
  const int wm = (wave >> 1) * 64, wn = (wave & 1) * 64;
  const int fr = lane & 15, q = lane >> 4;
  f32x4 acc[4][4]; zero_acc(acc);

  if (n < 1024) {
    const int xb = n & 7, yb = (n >> 3) & 31, b = n >> 8;
    const unsigned char* A  = (const unsigned char*)xnT8 + ((size_t)b * HW_ + yb * 128) * C_;
    const unsigned char* Bp = (const unsigned char*)wqkv8 + (size_t)xb * 128 * C_;
    gemm_bt_mx<false, 0x7F, 0x7B>(A, Bp, C_, C_, C_, acc, nullptr, As, Bs);
    const int r0 = yb * 128 + wm + (q << 2);
    const int cb = xb * 128 + wn;       // 64-col group base (true & stored)
    float bias[4];
#pragma unroll
    for (int j = 0; j < 4; ++j) bias[j] = qkv_b[cb + fr + j * 16];  // true cols
#pragma unroll
    for (int i = 0; i < 4; ++i)
#pragma unroll
      for (int r = 0; r < 4; ++r) {
        const int row = r0 + i * 16 + r;
        u32 dw = 0;
        dw = (u32)__builtin_amdgcn_cvt_pk_fp8_f32(acc[i][0][r] + bias[0],
                                                  acc[i][1][r] + bias[1], (int)dw, false);
        dw = (u32)__builtin_amdgcn_cvt_pk_fp8_f32(acc[i][2][r] + bias[2],
                                                  acc[i][3][r] + bias[3], (int)dw, true);
        *(u32*)((unsigned char*)QKt8 + ((size_t)b * HW_ + row) * 1024 + cb + fr * 4) = dw;
      }
  } else {
    const int m = n - 1024;
    const int xb = m & 31, yb = (m >> 5) & 3, b = m >> 7;
    const unsigned char* A  = (const unsigned char*)wqkv8 + (size_t)(1024 + yb * 128) * C_;
    const unsigned char* Bp = (const unsigned char*)xnT8 + ((size_t)b * HW_ + xb * 128) * C_;
    gemm_bt_mx<false, 0x7B, 0x7F>(A, Bp, C_, C_, C_, acc, nullptr, As, Bs);
    const int r0 = yb * 128 + wm + (q << 2);
    const int cb = xb * 128 + wn;       // hw 64-group base
#pragma unroll
    for (int i = 0; i < 4; ++i)
#pragma unroll
      for (int r = 0; r < 4; ++r) {
        const int row = r0 + i * 16 + r;        // c channel (row of V8)
        const float bias = qkv_b[1024 + row];
        u32 dw = 0;
        dw = (u32)__builtin_amdgcn_cvt_pk_fp8_f32(acc[i][0][r] + bias,
                                                  acc[i][1][r] + bias, (int)dw, false);
        dw = (u32)__builtin_amdgcn_cvt_pk_fp8_f32(acc[i][2][r] + bias,
                                                  acc[i][3][r] + bias, (int)dw, true);
        *(u32*)((unsigned char*)V8 + ((size_t)b * C_ + row) * HW_ + cb + fr * 4) = dw;
      }
  }
}

// P8[b][i][sigma-pos j] = fp8( 2^(scale*log2e * q_i.k_j - 4) ); MX-fp8 GEMM.
// XCD-aware 1-D grid: the 32 K-panel blocks sharing a Q row-panel are
// dispatch-adjacent on one XCD (QKt8 panels stay L2-hot per XCD). The whole
// (yb,b) output panel is produced on xcd = (b*32+yb)>>4 — pv exploits this.
__global__ void __launch_bounds__(256) sexp_gemm_kernel(const fp8_t* __restrict__ QKt8,
                                                        fp8_t* __restrict__ P8) {
  __shared__ __align__(16) unsigned char As[2 * 16384];
  __shared__ __align__(16) unsigned char Bs[2 * 16384];
  const int n   = blockIdx.x;            // 4096 blocks
  const int xcd = n & 7;
  const int p   = n >> 3;                // 0..511 within XCD
  const int xb  = p & 31;                // K panel (fastest -> share Q panel)
  const int grp = xcd * 16 + (p >> 5);   // 0..127 = (yb, b) combo
  const int yb  = grp & 31;              // Q panel
  const int b   = grp >> 5;              // batch

  const unsigned char* QKtb = (const unsigned char*)QKt8 + (size_t)b * HW_ * 1024;
  fp8_t* Pb = P8 + (size_t)b * HW_ * HW_;
  f32x4 acc[4][4]; zero_acc(acc);
  const unsigned char* A  = QKtb + (size_t)yb * 128 * 1024;        // Q rows
  const unsigned char* Bp = QKtb + 512 + (size_t)xb * 128 * 1024;  // K rows
  gemm_bt_mx<false>(A, Bp, 512, 1024, 1024, acc, nullptr, As, Bs);
  const int lane = threadIdx.x & 63, wave = threadIdx.x >> 6;
  const int wm = (wave >> 1) * 64, wn = (wave & 1) * 64;
  const int fr = lane & 15, q = lane >> 4;
  const int r0 = yb * 128 + wm + (q << 2);
  const int cb = xb * 128 + wn;          // j 64-group base
#pragma unroll
  for (int i = 0; i < 4; ++i)
#pragma unroll
    for (int r = 0; r < 4; ++r) {
      const int row = r0 + i * 16 + r;
      float e0 = fexp2(fmaf(acc[i][0][r], SEXPC_, -4.0f));
      float e1 = fexp2(fmaf(acc[i][1][r], SEXPC_, -4.0f));
      float e2 = fexp2(fmaf(acc[i][2][r], SEXPC_, -4.0f));
      float e3 = fexp2(fmaf(acc[i][3][r], SEXPC_, -4.0f));
      u32 dw = 0;
      dw = (u32)__builtin_amdgcn_cvt_pk_fp8_f32(e0, e1, (int)dw, false);
      dw = (u32)__builtin_amdgcn_cvt_pk_fp8_f32(e2, e3, (int)dw, true);
      *(u32*)((unsigned char*)Pb + (size_t)row * HW_ + cb + fr * 4) = dw;
    }
}

// hmT8[b][i][sigma-pos c] = fp8( 16 * (sum_j P8 * V8) / rowsum(P8) )
// MX-fp8 GEMM with ones-MFMA row sums. XCD map matches sexp's P-production
// map (same grp->(yb,b) formula => same xcd), with the within-XCD panel
// order REVERSED so pv consumes the last-written (L2-hot) panels first.
__global__ void __launch_bounds__(256) pv_gemm_kernel(const fp8_t* __restrict__ P8,
                                                      const fp8_t* __restrict__ V8,
                                                      fp8_t* __restrict__ hmT8) {
  __shared__ __align__(16) unsigned char As[2 * 16384];
  __shared__ __align__(16) unsigned char Bs[2 * 16384];
  // decode swizzled block id: n = 512 blocks total
  const int n   = blockIdx.x;
  const int xcd = n & 7;           // XCD (round-robin heuristic)
  const int p   = n >> 3;          // 0..63, position within XCD
  const int xb  = p & 3;           // C panel (fastest -> adjacent blocks share P)
  const int gi  = 15 - (p >> 2);   // REVERSED within-XCD group (hottest P first)
  const int grp = xcd * 16 + gi;   // 0..127 = (y,z) group
  const int yb  = grp & 31;        // HW panel
  const int b   = grp >> 5;        // batch

  const unsigned char* A  = (const unsigned char*)P8 + (size_t)b * HW_ * HW_ +
                            (size_t)yb * 128 * HW_;
  const unsigned char* Bp = (const unsigned char*)V8 + (size_t)b * C_ * HW_ +
                            (size_t)xb * 128 * HW_;
  fp8_t* hmTb = hmT8 + (size_t)b * HW_ * C_;

  f32x4 acc[4][4]; zero_acc(acc);
  f32x4 accl[4];
  {
    f32x4 z = {0.f, 0.f, 0.f, 0.f};
#pragma unroll
    for (int i = 0; i < 4; ++i) accl[i] = z;
  }
  gemm_bt_mx<true>(A, Bp, HW_, HW_, HW_, acc, accl, As, Bs);

  const int lane = threadIdx.x & 63, wave = threadIdx.x >> 6;
  const int wm = (wave >> 1) * 64, wn = (wave & 1) * 64;
  const int fr = lane & 15, q = lane >> 4;
  const int r0 = yb * 128 + wm + (q << 2);
  const int cb = xb * 128 + wn;   // c 64-group base (stored sigma-packed)
#pragma unroll
  for (int i = 0; i < 4; ++i)
#pragma unroll
    for (int r = 0; r < 4; ++r) {
      const int row = r0 + i * 16 + r;
      // x16 for fp8 range; undone by 2^-4 in proj. rcp: 1-ulp, fp8-invisible.
      const float rl = 16.f * __builtin_amdgcn_rcpf(accl[i][r]);
      u32 dw = 0;
      dw = (u32)__builtin_amdgcn_cvt_pk_fp8_f32(acc[i][0][r] * rl, acc[i][1][r] * rl, (int)dw, false);
      dw = (u32)__builtin_amdgcn_cvt_pk_fp8_f32(acc[i][2][r] * rl, acc[i][3][r] * rl, (int)dw, true);
      *(u32*)((unsigned char*)hmTb + (size_t)row * C_ + cb + fr * 4) = dw;
    }
}

// out[b][o][i] = x[b][o][i] + proj_b[o] + (wproj8*2^-4)(sigma) . (hmT8*2^-4)(sigma)
__global__ void __launch_bounds__(256) proj_gemm_kernel(const fp8_t* __restrict__ wproj8,
                                                        const fp8_t* __restrict__ hmT8,
                                                        const float* __restrict__ proj_b,
                                                        const float* __restrict__ x,
                                                        float* __restrict__ out) {
  __shared__ __align__(16) unsigned char As[2 * 16384];
  __shared__ __align__(16) unsigned char Bs[2 * 16384];
  const int b = blockIdx.z;
  f32x4 acc[4][4]; zero_acc(acc);
  const unsigned char* A  = (const unsigned char*)wproj8 + (size_t)blockIdx.y * 128 * C_;
  const unsigned char* Bp = (const unsigned char*)hmT8 + ((size_t)b * HW_ + blockIdx.x * 128) * C_;
  gemm_bt_mx<false, 0x7B, 0x7B>(A, Bp, C_, C_, C_, acc, nullptr, As, Bs);
  const int lane = threadIdx.x & 63, wave = threadIdx.x >> 6;
  const int wm = (wave >> 1) * 64, wn = (wave & 1) * 64;
  const int r0 = blockIdx.y * 128 + wm + ((lane >> 4) << 2);
  const int c0 = blockIdx.x * 128 + wn + (lane & 15);
#pragma unroll
  for (int i = 0; i < 4; ++i)
#pragma unroll
    for (int r = 0; r < 4; ++r) {
      const int row = r0 + i * 16 + r;
      const float bias = proj_b[row];
#pragma unroll
      for (int j = 0; j < 4; ++j) {
        const int col = c0 + j * 16;
        const size_t idx = ((size_t)b * C_ + row) * HW_ + col;
        out[idx] = x[idx] + bias + acc[i][j][r];
      }
    }
}

// ---------------- launch ----------------
// Workspace layout (bytes), total ~110 MB:
//   wqkv8  fp8 [1536][512] (x16)         786,432
//   wproj8 fp8 [512][512] (x16, sigma)   262,144
//   stats  f32 [128][8][2]                 8,192
//   xnT8   fp8 [4][4096][512]          8,388,608
//   QKt8   fp8 [4][4096][1024](sig)   16,777,216
//   V8     fp8 [4][512][4096] (sig)    8,388,608
//   hmT8   fp8 [4][4096][512] (x16,sig) 8,388,608
//   P8     fp8 [4][4096][4096](sig)   67,108,864
extern "C" void kernel_launch(void* const* d_in, const int* in_sizes, int n_in,
                              void* d_out, int out_size, void* d_ws, size_t ws_size,
                              hipStream_t stream) {
  const float* x      = (const float*)d_in[0];
  const float* norm_w = (const float*)d_in[1];
  const float* norm_b = (const float*)d_in[2];
  const float* qkv_w  = (const float*)d_in[3];
  const float* qkv_b  = (const float*)d_in[4];
  const float* proj_w = (const float*)d_in[5];
  const float* proj_b = (const float*)d_in[6];
  float* out = (float*)d_out;

  char* ws = (char*)d_ws;
  size_t o = 0;
  fp8_t* wqkv8  = (fp8_t*)(ws + o); o += (size_t)1536 * 512;
  fp8_t* wproj8 = (fp8_t*)(ws + o); o += (size_t)512 * 512;
  float* stats  = (float*)(ws + o); o += 128 * 8 * 2 * 4;
  fp8_t* xnT8   = (fp8_t*)(ws + o); o += (size_t)B_ * HW_ * C_;
  fp8_t* QKt8   = (fp8_t*)(ws + o); o += (size_t)B_ * HW_ * 1024;
  fp8_t* V8     = (fp8_t*)(ws + o); o += (size_t)B_ * C_ * HW_;
  fp8_t* hmT8   = (fp8_t*)(ws + o); o += (size_t)B_ * HW_ * C_;
  fp8_t* P8     = (fp8_t*)(ws + o); o += (size_t)B_ * HW_ * HW_;

  prep_kernel<<<2048, 256, 0, stream>>>(x, stats, qkv_w, proj_w, wqkv8, wproj8);
  norm_tr_kernel<<<dim3(HW_ / 64, C_ / 64, B_), 256, 0, stream>>>(x, stats, norm_w, norm_b, xnT8);
  qkv_gemm_kernel<<<1536, 256, 0, stream>>>(xnT8, wqkv8, qkv_b, QKt8, V8);
  sexp_gemm_kernel<<<4096, 256, 0, stream>>>(QKt8, P8);
  pv_gemm_kernel<<<512, 256, 0, stream>>>(P8, V8, hmT8);
  proj_gemm_kernel<<<dim3(HW_ / 128, C_ / 128, B_), 256, 0, stream>>>(
      wproj8, hmT8, proj_b, x, out);
}